// Round 4
// baseline (775.162 us; speedup 1.0000x reference)
//
#include <hip/hip_runtime.h>

// NeuralODE: z0 = enc(y0); 100 x Tsit5 steps of f = W3 tanh(W2 tanh(W1 y + b1) + b2) + b3;
// outputs ys = dec(z_t), zs = z_t.  One wave (64 thr) per TWO 16-batch groups, grid 128.
//
// === Chain-shortening algebra (round 3) ===
// Track u = TS*(W1 y + b1) (32-dim).  M = TS*W1*W3 (32x32 fused), c0 = TS*W1*b3.
// Per stage: h1=tanh(p); q=TSW2 h1+TSb2; h2=tanh(q); m=M h2; running accumulators
// U,P3..P6 build the next stage inputs.  z materialized once per step off-path:
// z += W3*(sum dtB_i h2_i) + dt*b3 (only for outputs).
//
// === ILP interleave (this revision) ===
// Latency-bound at 1 wave/SIMD (VALUBusy 19%, MfmaUtil 5%): ~75% of wall is exposed
// dependency latency.  Two INDEPENDENT batch chains per wave, interleaved at operation
// level (chain loop innermost, fully unrolled): each chain's stalls are filled by the
// other's issue.  Weights/M/decoder fragments shared across chains.
//
// GEMM orientation: D[row, elem] = W[row, k] * Act[k, elem] with mfma_f32_16x16x32_f16.
// Lane l = (e = l&15, q = l>>4). C/D: lane holds rows p = 16t+4q+r.
// Consumer weight k-columns pre-shuffled by kappa so producer C/D registers ARE the
// consumer's lane-local B-fragment: A-frag slot j <- W[row][16*(j>>2)+4*q+(j&3)].
// 3-term f16 hi/lo split (Whi*Bhi+Wlo*Bhi+Whi*Blo) keeps per-product error ~2^-22;
// m stays f32 so tiny Butcher coefficients never pass through f16.

typedef __attribute__((ext_vector_type(8))) _Float16 half8;
typedef __attribute__((ext_vector_type(4))) float f32x4;

static constexpr int TN = 101;
static constexpr int BN = 4096;

#define MFMA(a, b, c) __builtin_amdgcn_mfma_f32_16x16x32_f16((a), (b), (c), 0, 0, 0)

__device__ __forceinline__ float tanh_pre(float x) {
  // input already scaled by 2/ln2: tanh = 1 - 2/(1+2^x); exact at +/-inf via exp2 range.
  float e = __builtin_amdgcn_exp2f(x);
  float r = __builtin_amdgcn_rcpf(e + 1.0f);
  return __builtin_fmaf(-2.0f, r, 1.0f);
}

__device__ __forceinline__ void split8(const float* v, half8& hi, half8& lo) {
#pragma unroll
  for (int j = 0; j < 8; ++j) {
    _Float16 h = (_Float16)v[j];
    hi[j] = h;
    lo[j] = (_Float16)(v[j] - (float)h);
  }
}

// A-fragment for a weight whose k-columns are consumed kappa-shuffled:
// slot j of lane q, K-tile kt  <-  W[row][kt*32 + 16*(j>>2) + 4*q + (j&3)] * scale
__device__ __forceinline__ void load_wfrag(const float* __restrict__ W, int C, int row, int q,
                                           int kt, float scale, half8& hi, half8& lo) {
  const float* p = W + row * C + kt * 32 + 4 * q;
  float v[8] __attribute__((aligned(16)));
  *(f32x4*)(v) = *(const f32x4*)(p);
  *(f32x4*)(v + 4) = *(const f32x4*)(p + 16);
#pragma unroll
  for (int j = 0; j < 8; ++j) v[j] *= scale;
  split8(v, hi, lo);
}

__global__ __launch_bounds__(64, 1) void node_kernel(
    const float* __restrict__ ts, const float* __restrict__ y0,
    const float* __restrict__ encW, const float* __restrict__ encb,
    const float* __restrict__ W1, const float* __restrict__ b1,
    const float* __restrict__ W2, const float* __restrict__ b2,
    const float* __restrict__ W3, const float* __restrict__ b3,
    const float* __restrict__ decW, const float* __restrict__ decb,
    float* __restrict__ out) {
  const int l = threadIdx.x;
  const int lm = l & 15;
  const int q = l >> 4;
  const int eg0 = blockIdx.x * 32 + lm;  // chain c handles batch eg0 + 16*c

  const float TS = 2.8853900817779268f;  // 2/ln2

  // ---- dt and dt-folded Butcher coefficients ----
  const float dt = (ts[TN - 1] - ts[0]) / (float)(TN - 1);
  const float c21 = dt * 0.161f;
  const float c31 = dt * -0.008480655492356989f, c32 = dt * 0.335480655492357f;
  const float c41 = dt * 2.8971530571054935f, c42 = dt * -6.359448489975075f,
              c43 = dt * 4.3622954328695815f;
  const float c51 = dt * 5.325864828439257f, c52 = dt * -11.748883564062828f,
              c53 = dt * 7.4955393428898365f, c54 = dt * -0.09249506636175525f;
  const float c61 = dt * 5.86145544294642f, c62 = dt * -12.92096931784711f,
              c63 = dt * 8.159367898576159f, c64 = dt * -0.071584973281401f,
              c65 = dt * -0.028269050394068383f;
  const float d1 = dt * 0.09646076681806523f, d2 = dt * 0.01f, d3 = dt * 0.4798896504144996f,
              d4 = dt * 1.379008574103742f, d5 = dt * -3.290069515436081f,
              d6 = dt * 2.324710524099774f;
  const float sg3 = dt * 0.327f, sg4 = dt * 0.9f, sg5 = dt * 0.9800255409045097f,
              sg6 = dt * 1.0f;

  // ---- persistent weight fragments (shared across both chains) ----
  half8 w2h[2], w2l[2], w3h[4], w3l[4];
#pragma unroll
  for (int mt = 0; mt < 2; ++mt) load_wfrag(W2, 32, 16 * mt + lm, q, 0, TS, w2h[mt], w2l[mt]);
#pragma unroll
  for (int mt = 0; mt < 4; ++mt) load_wfrag(W3, 32, 16 * mt + lm, q, 0, 1.0f, w3h[mt], w3l[mt]);

  f32x4 b2f[2], db3f[4];
#pragma unroll
  for (int mt = 0; mt < 2; ++mt) {
    f32x4 t2 = *(const f32x4*)(b2 + 16 * mt + 4 * q);
#pragma unroll
    for (int r = 0; r < 4; ++r) t2[r] *= TS;
    b2f[mt] = t2;
  }
#pragma unroll
  for (int mt = 0; mt < 4; ++mt) {
    f32x4 t3 = *(const f32x4*)(b3 + 16 * mt + 4 * q);
#pragma unroll
    for (int r = 0; r < 4; ++r) t3[r] *= dt;
    db3f[mt] = t3;
  }

  // ---- decoder frags in registers (single f16: decoder error does not feed back) ----
  half8 dech[4][2];
  f32x4 decbf[4];
#pragma unroll
  for (int mt = 0; mt < 4; ++mt) {
#pragma unroll
    for (int kt = 0; kt < 2; ++kt) {
      const float* p = decW + (16 * mt + lm) * 64 + kt * 32 + 4 * q;
      float v[8] __attribute__((aligned(16)));
      *(f32x4*)(v) = *(const f32x4*)(p);
      *(f32x4*)(v + 4) = *(const f32x4*)(p + 16);
      half8 h;
#pragma unroll
      for (int j = 0; j < 8; ++j) h[j] = (_Float16)v[j];
      dech[mt][kt] = h;
    }
    decbf[mt] = *(const f32x4*)(decb + 16 * mt + 4 * q);
  }

  // ---- fused M = TS * W1 * W3 (A-frag layout, f32 dots -> hi/lo split) ----
  half8 Mh[2], Ml[2];
  {
    float Mv0[8] = {0, 0, 0, 0, 0, 0, 0, 0};
    float Mv1[8] = {0, 0, 0, 0, 0, 0, 0, 0};
    const float* w1a = W1 + (size_t)lm * 64;
    const float* w1b = W1 + (size_t)(16 + lm) * 64;
    for (int k = 0; k < 64; ++k) {
      float a = w1a[k], b = w1b[k];
      const float* w3r = W3 + (size_t)k * 32 + 4 * q;
#pragma unroll
      for (int jj = 0; jj < 2; ++jj) {
#pragma unroll
        for (int r = 0; r < 4; ++r) {
          float w3v = w3r[16 * jj + r];
          Mv0[4 * jj + r] = __builtin_fmaf(a, w3v, Mv0[4 * jj + r]);
          Mv1[4 * jj + r] = __builtin_fmaf(b, w3v, Mv1[4 * jj + r]);
        }
      }
    }
#pragma unroll
    for (int j = 0; j < 8; ++j) {
      Mv0[j] *= TS;
      Mv1[j] *= TS;
    }
    split8(Mv0, Mh[0], Ml[0]);
    split8(Mv1, Mh[1], Ml[1]);
  }

  // ---- c0 = TS * W1 * b3 in C/D layout: rows 16*mt + 4*q + r ----
  float c0[8] = {0, 0, 0, 0, 0, 0, 0, 0};
  {
    for (int k = 0; k < 64; ++k) {
      float bk = b3[k];
#pragma unroll
      for (int mt = 0; mt < 2; ++mt)
#pragma unroll
        for (int r = 0; r < 4; ++r)
          c0[4 * mt + r] =
              __builtin_fmaf(W1[(size_t)(16 * mt + 4 * q + r) * 64 + k], bk, c0[4 * mt + r]);
    }
#pragma unroll
    for (int j = 0; j < 8; ++j) c0[j] *= TS;
  }

  // ---- encoder: z0 = encW * y0^T + encb, both chains ----
  f32x4 zf[2][4];
#pragma unroll
  for (int c = 0; c < 2; ++c) {
    const float* yp = y0 + (size_t)(eg0 + 16 * c) * 64;
    float v[16] __attribute__((aligned(16)));
    *(f32x4*)(v) = *(const f32x4*)(yp + 8 * q);
    *(f32x4*)(v + 4) = *(const f32x4*)(yp + 8 * q + 4);
    *(f32x4*)(v + 8) = *(const f32x4*)(yp + 32 + 8 * q);
    *(f32x4*)(v + 12) = *(const f32x4*)(yp + 32 + 8 * q + 4);
    half8 xh[2], xl[2];
    split8(v, xh[0], xl[0]);
    split8(v + 8, xh[1], xl[1]);
#pragma unroll
    for (int mt = 0; mt < 4; ++mt) {
      const float* p0 = encW + (16 * mt + lm) * 64 + 8 * q;
      float w[8] __attribute__((aligned(16)));
      half8 eh, el;
      f32x4 a = *(const f32x4*)(encb + 16 * mt + 4 * q);
      *(f32x4*)(w) = *(const f32x4*)(p0);
      *(f32x4*)(w + 4) = *(const f32x4*)(p0 + 4);
      split8(w, eh, el);
      a = MFMA(eh, xh[0], a);
      a = MFMA(el, xh[0], a);
      a = MFMA(eh, xl[0], a);
      *(f32x4*)(w) = *(const f32x4*)(p0 + 32);
      *(f32x4*)(w + 4) = *(const f32x4*)(p0 + 36);
      split8(w, eh, el);
      a = MFMA(eh, xh[1], a);
      a = MFMA(el, xh[1], a);
      a = MFMA(eh, xl[1], a);
      zf[c][mt] = a;
    }
  }

  // ---- u0 = TS*(W1 z0 + b1), both chains via one transient W1 frag load ----
  float u[2][8];
  {
    half8 t1h[2][2], t1l[2][2];
    f32x4 tb1[2];
#pragma unroll
    for (int mt = 0; mt < 2; ++mt) {
#pragma unroll
      for (int kt = 0; kt < 2; ++kt)
        load_wfrag(W1, 64, 16 * mt + lm, q, kt, TS, t1h[mt][kt], t1l[mt][kt]);
      f32x4 t1 = *(const f32x4*)(b1 + 16 * mt + 4 * q);
#pragma unroll
      for (int r = 0; r < 4; ++r) t1[r] *= TS;
      tb1[mt] = t1;
    }
#pragma unroll
    for (int c = 0; c < 2; ++c) {
      float zv[16];
#pragma unroll
      for (int mt = 0; mt < 4; ++mt)
#pragma unroll
        for (int r = 0; r < 4; ++r) zv[4 * mt + r] = zf[c][mt][r];
      half8 yh[2], yl[2];
      split8(zv, yh[0], yl[0]);
      split8(zv + 8, yh[1], yl[1]);
#pragma unroll
      for (int mt = 0; mt < 2; ++mt) {
        f32x4 a = tb1[mt];
        a = MFMA(t1h[mt][0], yh[0], a);
        a = MFMA(t1l[mt][0], yh[0], a);
        a = MFMA(t1h[mt][0], yl[0], a);
        a = MFMA(t1h[mt][1], yh[1], a);
        a = MFMA(t1l[mt][1], yh[1], a);
        a = MFMA(t1h[mt][1], yl[1], a);
#pragma unroll
        for (int r = 0; r < 4; ++r) u[c][4 * mt + r] = a[r];
      }
    }
  }

  // ---- output helpers ----
  auto store_z = [&](int s) {
#pragma unroll
    for (int c = 0; c < 2; ++c) {
      float* zb = out + (size_t)BN * TN * 64 + ((size_t)(eg0 + 16 * c) * TN + s) * 64;
#pragma unroll
      for (int mt = 0; mt < 4; ++mt) *(f32x4*)(zb + 16 * mt + 4 * q) = zf[c][mt];
    }
  };
  auto dec_store = [&](int s) {
#pragma unroll
    for (int c = 0; c < 2; ++c) {
      half8 xh[2];
#pragma unroll
      for (int j = 0; j < 4; ++j) {
        xh[0][j] = (_Float16)zf[c][0][j];
        xh[0][4 + j] = (_Float16)zf[c][1][j];
        xh[1][j] = (_Float16)zf[c][2][j];
        xh[1][4 + j] = (_Float16)zf[c][3][j];
      }
      float* yb = out + ((size_t)(eg0 + 16 * c) * TN + s) * 64;
#pragma unroll
      for (int mt = 0; mt < 4; ++mt) {
        f32x4 a = decbf[mt];
        a = MFMA(dech[mt][0], xh[0], a);
        a = MFMA(dech[mt][1], xh[1], a);
        *(f32x4*)(yb + 16 * mt + 4 * q) = a;
      }
    }
  };

  // ---- per-stage core, both chains interleaved (chain loop innermost) ----
  auto layerchain2 = [&](const float (&pin)[2][8], float (&h2o)[2][8], float (&mo)[2][8]) {
    float h1[2][8];
#pragma unroll
    for (int c = 0; c < 2; ++c)
#pragma unroll
      for (int j = 0; j < 8; ++j) h1[c][j] = tanh_pre(pin[c][j]);
    half8 hh[2], hl[2];
    split8(h1[0], hh[0], hl[0]);
    split8(h1[1], hh[1], hl[1]);
    float qv[2][8];
#pragma unroll
    for (int mt = 0; mt < 2; ++mt) {
      f32x4 a0 = b2f[mt], a1 = b2f[mt];
      a0 = MFMA(w2h[mt], hh[0], a0);
      a1 = MFMA(w2h[mt], hh[1], a1);
      a0 = MFMA(w2l[mt], hh[0], a0);
      a1 = MFMA(w2l[mt], hh[1], a1);
      a0 = MFMA(w2h[mt], hl[0], a0);
      a1 = MFMA(w2h[mt], hl[1], a1);
#pragma unroll
      for (int r = 0; r < 4; ++r) {
        qv[0][4 * mt + r] = a0[r];
        qv[1][4 * mt + r] = a1[r];
      }
    }
#pragma unroll
    for (int c = 0; c < 2; ++c)
#pragma unroll
      for (int j = 0; j < 8; ++j) h2o[c][j] = tanh_pre(qv[c][j]);
    half8 th[2], tl[2];
    split8(h2o[0], th[0], tl[0]);
    split8(h2o[1], th[1], tl[1]);
#pragma unroll
    for (int mt = 0; mt < 2; ++mt) {
      f32x4 a0 = {0.0f, 0.0f, 0.0f, 0.0f}, a1 = {0.0f, 0.0f, 0.0f, 0.0f};
      a0 = MFMA(Mh[mt], th[0], a0);
      a1 = MFMA(Mh[mt], th[1], a1);
      a0 = MFMA(Ml[mt], th[0], a0);
      a1 = MFMA(Ml[mt], th[1], a1);
      a0 = MFMA(Mh[mt], tl[0], a0);
      a1 = MFMA(Mh[mt], tl[1], a1);
#pragma unroll
      for (int r = 0; r < 4; ++r) {
        mo[0][4 * mt + r] = a0[r];
        mo[1][4 * mt + r] = a1[r];
      }
    }
  };

  float H[2][8];  // sum_i dtB_i * h2_i (drives z materialization)

  // ---- one full Tsit5 step in u-space, both chains ----
  auto stages = [&]() {
    float U[2][8], P3[2][8], P4[2][8], P5[2][8], P6[2][8], p[2][8], h2[2][8], m[2][8];
#pragma unroll
    for (int c = 0; c < 2; ++c)
#pragma unroll
      for (int j = 0; j < 8; ++j) {
        U[c][j] = __builtin_fmaf(dt, c0[j], u[c][j]);
        P3[c][j] = __builtin_fmaf(sg3, c0[j], u[c][j]);
        P4[c][j] = __builtin_fmaf(sg4, c0[j], u[c][j]);
        P5[c][j] = __builtin_fmaf(sg5, c0[j], u[c][j]);
        P6[c][j] = __builtin_fmaf(sg6, c0[j], u[c][j]);
      }
    layerchain2(u, h2, m);  // stage 1
#pragma unroll
    for (int c = 0; c < 2; ++c)
#pragma unroll
      for (int j = 0; j < 8; ++j) {
        H[c][j] = d1 * h2[c][j];
        U[c][j] = __builtin_fmaf(d1, m[c][j], U[c][j]);
        P3[c][j] = __builtin_fmaf(c31, m[c][j], P3[c][j]);
        P4[c][j] = __builtin_fmaf(c41, m[c][j], P4[c][j]);
        P5[c][j] = __builtin_fmaf(c51, m[c][j], P5[c][j]);
        P6[c][j] = __builtin_fmaf(c61, m[c][j], P6[c][j]);
        p[c][j] = __builtin_fmaf(c21, c0[j] + m[c][j], u[c][j]);  // sig2 == c21
      }
    layerchain2(p, h2, m);  // stage 2
#pragma unroll
    for (int c = 0; c < 2; ++c)
#pragma unroll
      for (int j = 0; j < 8; ++j) {
        H[c][j] = __builtin_fmaf(d2, h2[c][j], H[c][j]);
        U[c][j] = __builtin_fmaf(d2, m[c][j], U[c][j]);
        P4[c][j] = __builtin_fmaf(c42, m[c][j], P4[c][j]);
        P5[c][j] = __builtin_fmaf(c52, m[c][j], P5[c][j]);
        P6[c][j] = __builtin_fmaf(c62, m[c][j], P6[c][j]);
        p[c][j] = __builtin_fmaf(c32, m[c][j], P3[c][j]);
      }
    layerchain2(p, h2, m);  // stage 3
#pragma unroll
    for (int c = 0; c < 2; ++c)
#pragma unroll
      for (int j = 0; j < 8; ++j) {
        H[c][j] = __builtin_fmaf(d3, h2[c][j], H[c][j]);
        U[c][j] = __builtin_fmaf(d3, m[c][j], U[c][j]);
        P5[c][j] = __builtin_fmaf(c53, m[c][j], P5[c][j]);
        P6[c][j] = __builtin_fmaf(c63, m[c][j], P6[c][j]);
        p[c][j] = __builtin_fmaf(c43, m[c][j], P4[c][j]);
      }
    layerchain2(p, h2, m);  // stage 4
#pragma unroll
    for (int c = 0; c < 2; ++c)
#pragma unroll
      for (int j = 0; j < 8; ++j) {
        H[c][j] = __builtin_fmaf(d4, h2[c][j], H[c][j]);
        U[c][j] = __builtin_fmaf(d4, m[c][j], U[c][j]);
        P6[c][j] = __builtin_fmaf(c64, m[c][j], P6[c][j]);
        p[c][j] = __builtin_fmaf(c54, m[c][j], P5[c][j]);
      }
    layerchain2(p, h2, m);  // stage 5
#pragma unroll
    for (int c = 0; c < 2; ++c)
#pragma unroll
      for (int j = 0; j < 8; ++j) {
        H[c][j] = __builtin_fmaf(d5, h2[c][j], H[c][j]);
        U[c][j] = __builtin_fmaf(d5, m[c][j], U[c][j]);
        p[c][j] = __builtin_fmaf(c65, m[c][j], P6[c][j]);
      }
    layerchain2(p, h2, m);  // stage 6
#pragma unroll
    for (int c = 0; c < 2; ++c)
#pragma unroll
      for (int j = 0; j < 8; ++j) {
        H[c][j] = __builtin_fmaf(d6, h2[c][j], H[c][j]);
        u[c][j] = __builtin_fmaf(d6, m[c][j], U[c][j]);  // u <- u_next
      }
  };

  // ---- z materialization for one step (off the u-chain): z += W3*H + dt*b3 ----
  auto zblock = [&](int s) {
    half8 Hh[2], Hl[2];
    split8(H[0], Hh[0], Hl[0]);
    split8(H[1], Hh[1], Hl[1]);
#pragma unroll
    for (int mt = 0; mt < 4; ++mt) {
      f32x4 a0 = zf[0][mt], a1 = zf[1][mt];
      a0 = MFMA(w3h[mt], Hh[0], a0);
      a1 = MFMA(w3h[mt], Hh[1], a1);
      a0 = MFMA(w3l[mt], Hh[0], a0);
      a1 = MFMA(w3l[mt], Hh[1], a1);
      a0 = MFMA(w3h[mt], Hl[0], a0);
      a1 = MFMA(w3h[mt], Hl[1], a1);
      zf[0][mt] = a0 + db3f[mt];
      zf[1][mt] = a1 + db3f[mt];
    }
    store_z(s);
    dec_store(s);
  };

  store_z(0);
  dec_store(0);

  stages();  // step 1
#pragma nounroll
  for (int s = 2; s < TN; ++s) {
    zblock(s - 1);  // materialize + store step s-1 (independent of the u-chain below)
    stages();
  }
  zblock(TN - 1);
}

extern "C" void kernel_launch(void* const* d_in, const int* in_sizes, int n_in,
                              void* d_out, int out_size, void* d_ws, size_t ws_size,
                              hipStream_t stream) {
  const float* ts = (const float*)d_in[0];
  const float* y0 = (const float*)d_in[1];
  const float* encW = (const float*)d_in[2];
  const float* encb = (const float*)d_in[3];
  const float* W1 = (const float*)d_in[4];
  const float* b1 = (const float*)d_in[5];
  const float* W2 = (const float*)d_in[6];
  const float* b2 = (const float*)d_in[7];
  const float* W3 = (const float*)d_in[8];
  const float* b3 = (const float*)d_in[9];
  const float* decW = (const float*)d_in[10];
  const float* decb = (const float*)d_in[11];
  node_kernel<<<BN / 32, 64, 0, stream>>>(ts, y0, encW, encb, W1, b1, W2, b2, W3, b3, decW,
                                          decb, (float*)d_out);
}

// Round 6
// 475.521 us; speedup vs baseline: 1.6301x; 1.6301x over previous
//
#include <hip/hip_runtime.h>

// NeuralODE: z0 = enc(y0); 100 x Tsit5 steps of f = W3 tanh(W2 tanh(W1 y + b1) + b2) + b3;
// outputs ys = dec(z_t), zs = z_t.  One wave (64 thr) per 16 batch elements, grid 256.
//
// === Chain-shortening algebra (round 3) ===
// Track u = TS*(W1 y + b1) (32-dim).  M = TS*W1*W3 (32x32 fused), c0 = TS*W1*b3.
// Per stage: h1=tanh(p); q=TSW2 h1+TSb2; h2=tanh(q); m=M h2; running accumulators
// U,P3..P6 build stage inputs.  z materialized once per step off-path:
// z += W3*(sum dtB_i h2_i) + dt*b3 (only for outputs).
//
// === Issue-count reduction (round 5; re-run — infra failure last round) ===
// Empirical model from r1-r4: wall ~ per-wave instruction count (r4: 2x work = exactly
// 2x wall, zero overlap; r3: -40% issue = -39% wall).  So: halve the scalar bookkeeping.
//  - all per-lane f32 state is f32x2; Butcher/accumulator updates via
//    __builtin_elementwise_fma -> v_pk_fma_f32 (full-rate packed f32, CDNA2+)
//  - hi/lo splits via v_cvt_pkrtz_f16_f32 (packed cvt): 20 ops vs ~30.  RTZ hi is safe:
//    lo captures the exact residual, reconstruction ~2^-22 independent of rounding mode.
//
// GEMM orientation: D[row, elem] = W[row, k] * Act[k, elem] with mfma_f32_16x16x32_f16.
// Lane l = (e = l&15, q = l>>4). C/D: lane holds rows p = 16t+4q+r.
// Consumer weight k-columns pre-shuffled by kappa so producer C/D registers ARE the
// consumer's lane-local B-fragment: A-frag slot j <- W[row][16*(j>>2)+4*q+(j&3)].
// 3-term f16 hi/lo split (Whi*Bhi+Wlo*Bhi+Whi*Blo) keeps per-product error ~2^-22;
// m stays f32 so tiny Butcher coefficients never pass through f16.

typedef __attribute__((ext_vector_type(8))) _Float16 half8;
typedef __attribute__((ext_vector_type(2))) _Float16 half2;
typedef __attribute__((ext_vector_type(4))) float f32x4;
typedef __attribute__((ext_vector_type(2))) float f32x2;

static constexpr int TN = 101;
static constexpr int BN = 4096;

#define MFMA(a, b, c) __builtin_amdgcn_mfma_f32_16x16x32_f16((a), (b), (c), 0, 0, 0)

union H8 {
  half8 v8;
  half2 v2[4];
};
union F4 {
  f32x4 v4;
  f32x2 v2[2];
};

__device__ __forceinline__ float tanh_pre(float x) {
  // input already scaled by 2/ln2: tanh = 1 - 2/(1+2^x); exact at +/-inf via exp2 range.
  float e = __builtin_amdgcn_exp2f(x);
  float r = __builtin_amdgcn_rcpf(e + 1.0f);
  return __builtin_fmaf(-2.0f, r, 1.0f);
}

__device__ __forceinline__ f32x2 pkfma(float c, f32x2 a, f32x2 b) {
  return __builtin_elementwise_fma((f32x2){c, c}, a, b);  // v_pk_fma_f32
}

// packed hi/lo split of 8 f32 (as f32x2[4], linear order preserved)
__device__ __forceinline__ void split8pk(const f32x2 (&w)[4], half8& hi, half8& lo) {
  H8 h, l;
#pragma unroll
  for (int i = 0; i < 4; ++i) {
    auto ph = __builtin_amdgcn_cvt_pkrtz(w[i][0], w[i][1]);  // v_cvt_pkrtz_f16_f32
    h.v2[i][0] = ph[0];
    h.v2[i][1] = ph[1];
    f32x2 back = {(float)ph[0], (float)ph[1]};
    f32x2 res = w[i] - back;  // v_pk_add_f32
    auto pl = __builtin_amdgcn_cvt_pkrtz(res[0], res[1]);
    l.v2[i][0] = pl[0];
    l.v2[i][1] = pl[1];
  }
  hi = h.v8;
  lo = l.v8;
}

__device__ __forceinline__ void split8(const float* v, half8& hi, half8& lo) {
#pragma unroll
  for (int j = 0; j < 8; ++j) {
    _Float16 h = (_Float16)v[j];
    hi[j] = h;
    lo[j] = (_Float16)(v[j] - (float)h);
  }
}

// A-fragment for a weight whose k-columns are consumed kappa-shuffled:
// slot j of lane q, K-tile kt  <-  W[row][kt*32 + 16*(j>>2) + 4*q + (j&3)] * scale
__device__ __forceinline__ void load_wfrag(const float* __restrict__ W, int C, int row, int q,
                                           int kt, float scale, half8& hi, half8& lo) {
  const float* p = W + row * C + kt * 32 + 4 * q;
  float v[8] __attribute__((aligned(16)));
  *(f32x4*)(v) = *(const f32x4*)(p);
  *(f32x4*)(v + 4) = *(const f32x4*)(p + 16);
#pragma unroll
  for (int j = 0; j < 8; ++j) v[j] *= scale;
  split8(v, hi, lo);
}

__global__ __launch_bounds__(64, 1) void node_kernel(
    const float* __restrict__ ts, const float* __restrict__ y0,
    const float* __restrict__ encW, const float* __restrict__ encb,
    const float* __restrict__ W1, const float* __restrict__ b1,
    const float* __restrict__ W2, const float* __restrict__ b2,
    const float* __restrict__ W3, const float* __restrict__ b3,
    const float* __restrict__ decW, const float* __restrict__ decb,
    float* __restrict__ out) {
  const int l = threadIdx.x;
  const int lm = l & 15;
  const int q = l >> 4;
  const int eg = blockIdx.x * 16 + lm;

  const float TS = 2.8853900817779268f;  // 2/ln2

  // ---- dt and dt-folded Butcher coefficients ----
  const float dt = (ts[TN - 1] - ts[0]) / (float)(TN - 1);
  const float c21 = dt * 0.161f;
  const float c31 = dt * -0.008480655492356989f, c32 = dt * 0.335480655492357f;
  const float c41 = dt * 2.8971530571054935f, c42 = dt * -6.359448489975075f,
              c43 = dt * 4.3622954328695815f;
  const float c51 = dt * 5.325864828439257f, c52 = dt * -11.748883564062828f,
              c53 = dt * 7.4955393428898365f, c54 = dt * -0.09249506636175525f;
  const float c61 = dt * 5.86145544294642f, c62 = dt * -12.92096931784711f,
              c63 = dt * 8.159367898576159f, c64 = dt * -0.071584973281401f,
              c65 = dt * -0.028269050394068383f;
  const float d1 = dt * 0.09646076681806523f, d2 = dt * 0.01f, d3 = dt * 0.4798896504144996f,
              d4 = dt * 1.379008574103742f, d5 = dt * -3.290069515436081f,
              d6 = dt * 2.324710524099774f;
  const float sg3 = dt * 0.327f, sg4 = dt * 0.9f, sg5 = dt * 0.9800255409045097f,
              sg6 = dt * 1.0f;

  // ---- persistent weight fragments ----
  half8 w2h[2], w2l[2], w3h[4], w3l[4];
#pragma unroll
  for (int mt = 0; mt < 2; ++mt) load_wfrag(W2, 32, 16 * mt + lm, q, 0, TS, w2h[mt], w2l[mt]);
#pragma unroll
  for (int mt = 0; mt < 4; ++mt) load_wfrag(W3, 32, 16 * mt + lm, q, 0, 1.0f, w3h[mt], w3l[mt]);

  f32x4 b2f[2], db3f[4];
#pragma unroll
  for (int mt = 0; mt < 2; ++mt) {
    f32x4 t2 = *(const f32x4*)(b2 + 16 * mt + 4 * q);
#pragma unroll
    for (int r = 0; r < 4; ++r) t2[r] *= TS;
    b2f[mt] = t2;
  }
#pragma unroll
  for (int mt = 0; mt < 4; ++mt) {
    f32x4 t3 = *(const f32x4*)(b3 + 16 * mt + 4 * q);
#pragma unroll
    for (int r = 0; r < 4; ++r) t3[r] *= dt;
    db3f[mt] = t3;
  }

  // ---- decoder frags in registers (single f16: decoder error does not feed back) ----
  half8 dech[4][2];
  f32x4 decbf[4];
#pragma unroll
  for (int mt = 0; mt < 4; ++mt) {
#pragma unroll
    for (int kt = 0; kt < 2; ++kt) {
      const float* p = decW + (16 * mt + lm) * 64 + kt * 32 + 4 * q;
      float v[8] __attribute__((aligned(16)));
      *(f32x4*)(v) = *(const f32x4*)(p);
      *(f32x4*)(v + 4) = *(const f32x4*)(p + 16);
      half8 h;
#pragma unroll
      for (int j = 0; j < 8; ++j) h[j] = (_Float16)v[j];
      dech[mt][kt] = h;
    }
    decbf[mt] = *(const f32x4*)(decb + 16 * mt + 4 * q);
  }

  // ---- fused M = TS * W1 * W3 (A-frag layout, f32 dots -> hi/lo split) ----
  half8 Mh[2], Ml[2];
  {
    float Mv0[8] = {0, 0, 0, 0, 0, 0, 0, 0};
    float Mv1[8] = {0, 0, 0, 0, 0, 0, 0, 0};
    const float* w1a = W1 + (size_t)lm * 64;
    const float* w1b = W1 + (size_t)(16 + lm) * 64;
    for (int k = 0; k < 64; ++k) {
      float a = w1a[k], b = w1b[k];
      const float* w3r = W3 + (size_t)k * 32 + 4 * q;
#pragma unroll
      for (int jj = 0; jj < 2; ++jj) {
#pragma unroll
        for (int r = 0; r < 4; ++r) {
          float w3v = w3r[16 * jj + r];
          Mv0[4 * jj + r] = __builtin_fmaf(a, w3v, Mv0[4 * jj + r]);
          Mv1[4 * jj + r] = __builtin_fmaf(b, w3v, Mv1[4 * jj + r]);
        }
      }
    }
#pragma unroll
    for (int j = 0; j < 8; ++j) {
      Mv0[j] *= TS;
      Mv1[j] *= TS;
    }
    split8(Mv0, Mh[0], Ml[0]);
    split8(Mv1, Mh[1], Ml[1]);
  }

  // ---- c0 = TS * W1 * b3 in C/D layout: rows 16*mt + 4*q + r ----
  float c0s[8] = {0, 0, 0, 0, 0, 0, 0, 0};
  {
    for (int k = 0; k < 64; ++k) {
      float bk = b3[k];
#pragma unroll
      for (int mt = 0; mt < 2; ++mt)
#pragma unroll
        for (int r = 0; r < 4; ++r)
          c0s[4 * mt + r] =
              __builtin_fmaf(W1[(size_t)(16 * mt + 4 * q + r) * 64 + k], bk, c0s[4 * mt + r]);
    }
#pragma unroll
    for (int j = 0; j < 8; ++j) c0s[j] *= TS;
  }
  f32x2 c0[4];
#pragma unroll
  for (int i = 0; i < 4; ++i) c0[i] = (f32x2){c0s[2 * i], c0s[2 * i + 1]};

  // ---- encoder: z0 = encW * y0^T + encb ----
  f32x4 zf[4];
  {
    const float* yp = y0 + (size_t)eg * 64;
    float v[16] __attribute__((aligned(16)));
    *(f32x4*)(v) = *(const f32x4*)(yp + 8 * q);
    *(f32x4*)(v + 4) = *(const f32x4*)(yp + 8 * q + 4);
    *(f32x4*)(v + 8) = *(const f32x4*)(yp + 32 + 8 * q);
    *(f32x4*)(v + 12) = *(const f32x4*)(yp + 32 + 8 * q + 4);
    half8 xh[2], xl[2];
    split8(v, xh[0], xl[0]);
    split8(v + 8, xh[1], xl[1]);
#pragma unroll
    for (int mt = 0; mt < 4; ++mt) {
      const float* p0 = encW + (16 * mt + lm) * 64 + 8 * q;
      float w[8] __attribute__((aligned(16)));
      half8 eh, el;
      f32x4 a = *(const f32x4*)(encb + 16 * mt + 4 * q);
      *(f32x4*)(w) = *(const f32x4*)(p0);
      *(f32x4*)(w + 4) = *(const f32x4*)(p0 + 4);
      split8(w, eh, el);
      a = MFMA(eh, xh[0], a);
      a = MFMA(el, xh[0], a);
      a = MFMA(eh, xl[0], a);
      *(f32x4*)(w) = *(const f32x4*)(p0 + 32);
      *(f32x4*)(w + 4) = *(const f32x4*)(p0 + 36);
      split8(w, eh, el);
      a = MFMA(eh, xh[1], a);
      a = MFMA(el, xh[1], a);
      a = MFMA(eh, xl[1], a);
      zf[mt] = a;
    }
  }

  // ---- u0 = TS*(W1 z0 + b1) via transient L1 pass ----
  f32x2 u[4];
  {
    half8 t1h[2][2], t1l[2][2];
    f32x4 tb1[2];
#pragma unroll
    for (int mt = 0; mt < 2; ++mt) {
#pragma unroll
      for (int kt = 0; kt < 2; ++kt)
        load_wfrag(W1, 64, 16 * mt + lm, q, kt, TS, t1h[mt][kt], t1l[mt][kt]);
      f32x4 t1 = *(const f32x4*)(b1 + 16 * mt + 4 * q);
#pragma unroll
      for (int r = 0; r < 4; ++r) t1[r] *= TS;
      tb1[mt] = t1;
    }
    float zv[16];
#pragma unroll
    for (int mt = 0; mt < 4; ++mt)
#pragma unroll
      for (int r = 0; r < 4; ++r) zv[4 * mt + r] = zf[mt][r];
    half8 yh[2], yl[2];
    split8(zv, yh[0], yl[0]);
    split8(zv + 8, yh[1], yl[1]);
#pragma unroll
    for (int mt = 0; mt < 2; ++mt) {
      f32x4 a = tb1[mt];
      a = MFMA(t1h[mt][0], yh[0], a);
      a = MFMA(t1l[mt][0], yh[0], a);
      a = MFMA(t1h[mt][0], yl[0], a);
      a = MFMA(t1h[mt][1], yh[1], a);
      a = MFMA(t1l[mt][1], yh[1], a);
      a = MFMA(t1h[mt][1], yl[1], a);
#pragma unroll
      for (int r = 0; r < 4; ++r) u[2 * mt + (r >> 1)][r & 1] = a[r];
    }
  }

  // ---- output helpers (read zf) ----
  auto store_z = [&](int s) {
    float* zb = out + (size_t)BN * TN * 64 + ((size_t)eg * TN + s) * 64;
#pragma unroll
    for (int mt = 0; mt < 4; ++mt) *(f32x4*)(zb + 16 * mt + 4 * q) = zf[mt];
  };
  auto dec_store = [&](int s) {
    half8 xh[2];
#pragma unroll
    for (int j = 0; j < 4; ++j) {
      xh[0][j] = (_Float16)zf[0][j];
      xh[0][4 + j] = (_Float16)zf[1][j];
      xh[1][j] = (_Float16)zf[2][j];
      xh[1][4 + j] = (_Float16)zf[3][j];
    }
    float* yb = out + ((size_t)eg * TN + s) * 64;
#pragma unroll
    for (int mt = 0; mt < 4; ++mt) {
      f32x4 a = decbf[mt];
      a = MFMA(dech[mt][0], xh[0], a);
      a = MFMA(dech[mt][1], xh[1], a);
      *(f32x4*)(yb + 16 * mt + 4 * q) = a;
    }
  };

  // ---- per-stage core: h1=tanh(p); q=W2h1+b2; h2=tanh(q); m=M*h2 ----
  auto layerchain = [&](const f32x2 (&pin)[4], f32x2 (&h2o)[4], f32x2 (&mo)[4]) {
    f32x2 h1[4];
#pragma unroll
    for (int i = 0; i < 4; ++i) h1[i] = (f32x2){tanh_pre(pin[i][0]), tanh_pre(pin[i][1])};
    half8 hh, hl;
    split8pk(h1, hh, hl);
    f32x2 qv[4];
#pragma unroll
    for (int mt = 0; mt < 2; ++mt) {
      F4 a;
      a.v4 = b2f[mt];
      a.v4 = MFMA(w2h[mt], hh, a.v4);
      a.v4 = MFMA(w2l[mt], hh, a.v4);
      a.v4 = MFMA(w2h[mt], hl, a.v4);
      qv[2 * mt] = a.v2[0];
      qv[2 * mt + 1] = a.v2[1];
    }
#pragma unroll
    for (int i = 0; i < 4; ++i) h2o[i] = (f32x2){tanh_pre(qv[i][0]), tanh_pre(qv[i][1])};
    half8 th, tl;
    split8pk(h2o, th, tl);
#pragma unroll
    for (int mt = 0; mt < 2; ++mt) {
      F4 a;
      a.v4 = (f32x4){0.0f, 0.0f, 0.0f, 0.0f};
      a.v4 = MFMA(Mh[mt], th, a.v4);
      a.v4 = MFMA(Ml[mt], th, a.v4);
      a.v4 = MFMA(Mh[mt], tl, a.v4);
      mo[2 * mt] = a.v2[0];
      mo[2 * mt + 1] = a.v2[1];
    }
  };

  f32x2 H[4];  // sum_i dtB_i * h2_i (drives z materialization)

  // ---- one full Tsit5 step in u-space (all combos in v_pk_fma_f32) ----
  auto stages = [&]() {
    f32x2 U[4], P3[4], P4[4], P5[4], P6[4], p[4], h2[4], m[4];
#pragma unroll
    for (int i = 0; i < 4; ++i) {
      U[i] = pkfma(dt, c0[i], u[i]);
      P3[i] = pkfma(sg3, c0[i], u[i]);
      P4[i] = pkfma(sg4, c0[i], u[i]);
      P5[i] = pkfma(sg5, c0[i], u[i]);
      P6[i] = pkfma(sg6, c0[i], u[i]);
    }
    layerchain(u, h2, m);  // stage 1
#pragma unroll
    for (int i = 0; i < 4; ++i) {
      H[i] = (f32x2){d1, d1} * h2[i];
      U[i] = pkfma(d1, m[i], U[i]);
      P3[i] = pkfma(c31, m[i], P3[i]);
      P4[i] = pkfma(c41, m[i], P4[i]);
      P5[i] = pkfma(c51, m[i], P5[i]);
      P6[i] = pkfma(c61, m[i], P6[i]);
      p[i] = pkfma(c21, c0[i] + m[i], u[i]);  // sig2 == c21
    }
    layerchain(p, h2, m);  // stage 2
#pragma unroll
    for (int i = 0; i < 4; ++i) {
      H[i] = pkfma(d2, h2[i], H[i]);
      U[i] = pkfma(d2, m[i], U[i]);
      P4[i] = pkfma(c42, m[i], P4[i]);
      P5[i] = pkfma(c52, m[i], P5[i]);
      P6[i] = pkfma(c62, m[i], P6[i]);
      p[i] = pkfma(c32, m[i], P3[i]);
    }
    layerchain(p, h2, m);  // stage 3
#pragma unroll
    for (int i = 0; i < 4; ++i) {
      H[i] = pkfma(d3, h2[i], H[i]);
      U[i] = pkfma(d3, m[i], U[i]);
      P5[i] = pkfma(c53, m[i], P5[i]);
      P6[i] = pkfma(c63, m[i], P6[i]);
      p[i] = pkfma(c43, m[i], P4[i]);
    }
    layerchain(p, h2, m);  // stage 4
#pragma unroll
    for (int i = 0; i < 4; ++i) {
      H[i] = pkfma(d4, h2[i], H[i]);
      U[i] = pkfma(d4, m[i], U[i]);
      P6[i] = pkfma(c64, m[i], P6[i]);
      p[i] = pkfma(c54, m[i], P5[i]);
    }
    layerchain(p, h2, m);  // stage 5
#pragma unroll
    for (int i = 0; i < 4; ++i) {
      H[i] = pkfma(d5, h2[i], H[i]);
      U[i] = pkfma(d5, m[i], U[i]);
      p[i] = pkfma(c65, m[i], P6[i]);
    }
    layerchain(p, h2, m);  // stage 6
#pragma unroll
    for (int i = 0; i < 4; ++i) {
      H[i] = pkfma(d6, h2[i], H[i]);
      u[i] = pkfma(d6, m[i], U[i]);  // u <- u_next
    }
  };

  // ---- z materialization for one step (off the u-chain): z += W3*H + dt*b3 ----
  auto zblock = [&](int s) {
    half8 Hh, Hl;
    split8pk(H, Hh, Hl);
#pragma unroll
    for (int mt = 0; mt < 4; ++mt) {
      f32x4 a = zf[mt];
      a = MFMA(w3h[mt], Hh, a);
      a = MFMA(w3l[mt], Hh, a);
      a = MFMA(w3h[mt], Hl, a);
      zf[mt] = a + db3f[mt];
    }
    store_z(s);
    dec_store(s);
  };

  store_z(0);
  dec_store(0);

  stages();  // step 1
#pragma nounroll
  for (int s = 2; s < TN; ++s) {
    zblock(s - 1);  // materialize + store step s-1 (independent of the u-chain below)
    stages();
  }
  zblock(TN - 1);
}

extern "C" void kernel_launch(void* const* d_in, const int* in_sizes, int n_in,
                              void* d_out, int out_size, void* d_ws, size_t ws_size,
                              hipStream_t stream) {
  const float* ts = (const float*)d_in[0];
  const float* y0 = (const float*)d_in[1];
  const float* encW = (const float*)d_in[2];
  const float* encb = (const float*)d_in[3];
  const float* W1 = (const float*)d_in[4];
  const float* b1 = (const float*)d_in[5];
  const float* W2 = (const float*)d_in[6];
  const float* b2 = (const float*)d_in[7];
  const float* W3 = (const float*)d_in[8];
  const float* b3 = (const float*)d_in[9];
  const float* decW = (const float*)d_in[10];
  const float* decb = (const float*)d_in[11];
  node_kernel<<<BN / 16, 64, 0, stream>>>(ts, y0, encW, encb, W1, b1, W2, b2, W3, b3, decW,
                                          decb, (float*)d_out);
}